// Round 6
// baseline (78.694 us; speedup 1.0000x reference)
//
#include <hip/hip_runtime.h>
#include <hip/hip_bf16.h>

#define V 17
#define C_DIM 256
#define TV 1088        // T*V
#define CTV 278528     // C*T*V
#define YP 76          // y LDS pitch in floats

typedef __attribute__((ext_vector_type(8))) short short8;
typedef __attribute__((ext_vector_type(4))) float f32x4;

static __device__ inline short f2bfs(float f) {
    union { __hip_bfloat16 b; short s; } u;
    u.b = __float2bfloat16(f);
    return u.s;
}

// ws layout (bytes):
//   0      : wtb   (65536 bf16)   blocked B^T: wtb[(kc*256+d)*32+kk] = W[kc*32+kk][d]
//   131072 : g     (4352 f32)     tanh(fm)+1
//   148480 : soff  (4352 float2)  {scale, off}
__global__ __launch_bounds__(256) void prep_kernel(
    const float* __restrict__ fm, const float* __restrict__ W,
    const float* __restrict__ lb, const float* __restrict__ gamma,
    const float* __restrict__ beta, const float* __restrict__ mean,
    const float* __restrict__ var,
    __hip_bfloat16* __restrict__ wtb, float* __restrict__ g,
    float2* __restrict__ soff)
{
    int i = blockIdx.x * 256 + threadIdx.x;   // 65536 threads
    int c = i >> 8, d = i & 255;
    float w = W[i];
    wtb[((c >> 5) * 256 + d) * 32 + (c & 31)] = __float2bfloat16(w);
    if (i < V * C_DIM) {
        g[i] = tanhf(fm[i]) + 1.0f;
        float sc = gamma[i] * rsqrtf(var[i] + 1e-5f);
        soff[i] = make_float2(sc, (lb[d] - mean[i]) * sc + beta[i]);
    }
}

// One staging task: gather 8 channels for row r, gate, cast, one short8 LDS write.
static __device__ __forceinline__ void stage_task(
    int t, short* As, const float* __restrict__ xplane, const float* __restrict__ g)
{
    int kkc = t / 68;                  // 0..31 (16B slot index)
    int r   = t - kkc * 68;            // 0..67
    int tl  = r / 17;
    int u   = r - tl * 17;
    int c0  = kkc * 8;
    const float* gp = g + u * C_DIM + c0;
    float4 g0 = *(const float4*)gp;
    float4 g1 = *(const float4*)(gp + 4);
    float gg[8] = {g0.x, g0.y, g0.z, g0.w, g1.x, g1.y, g1.z, g1.w};
    const float* xb = xplane + tl * V;
    int mm = (u + c0) % V;
    float xv[8];
    #pragma unroll
    for (int i = 0; i < 8; ++i) {
        xv[i] = xb[(c0 + i) * TV + mm];
        mm = (mm == V - 1) ? 0 : mm + 1;
    }
    short av[8];
    #pragma unroll
    for (int i = 0; i < 8; ++i) av[i] = f2bfs(xv[i] * gg[i]);
    *(short8*)(As + r * 256 + ((kkc ^ (r & 7)) << 3)) =
        (short8){av[0], av[1], av[2], av[3], av[4], av[5], av[6], av[7]};
}

// Block: 4 whole t-groups (68 rows, padded to 80), all 256 d. 512 thr / 8 waves.
// A-tile LDS: [80 rows][256 halves], 16B-slot XOR swizzle (slot ^= row&7).
// __launch_bounds__(512,6): cap total regs/wave at ~85 (acc=40 AGPR + ~45 VGPR)
// so 3 blocks (24 waves) co-reside per CU instead of 2.
__global__ __launch_bounds__(512, 6) void shiftgcn_kernel(
    const float* __restrict__ x0, const __hip_bfloat16* __restrict__ wtb,
    const float* __restrict__ g, const float2* __restrict__ soff,
    float* __restrict__ out)
{
    __shared__ __align__(16) char smem[80 * 256 * 2];   // 40960 B
    short* As = (short*)smem;                 // [80 rows][256 halves], swizzled
    float* Ys = (float*)smem;                 // epilogue union: [8 waves][16 d][YP]

    const int tid  = threadIdx.x;
    const int lane = tid & 63;
    const int wv   = tid >> 6;                // 0..7
    const int l15  = lane & 15;
    const int lq   = lane >> 4;

    // T1: 1024 wg = 8 XCD x 128 contiguous tiles (bijective)
    const int wg  = (blockIdx.x & 7) * 128 + (blockIdx.x >> 3);
    const int nt0 = wg * 4;
    const int n   = nt0 >> 6;
    const int tb  = nt0 & 63;                 // multiple of 4
    const float* xplane = x0 + n * CTV + tb * V;   // + c*TV + tl*V + joint

    // zero pad rows 68..79 (12 rows * 256 halves = 384 short8)
    if (tid < 384) ((short8*)(As + 68 * 256))[tid] = (short8)0;

    // ---- Phase 1: stage all K. 2176 tasks = 4 full rounds + 128-thread tail.
    #pragma unroll 1
    for (int it = 0; it < 4; ++it)
        stage_task(it * 512 + tid, As, xplane, g);
    if (tid < 128)
        stage_task(2048 + tid, As, xplane, g);
    __syncthreads();

    // ---- Phase 2: MFMA, no barriers. Wave wv owns cols [wv*32, wv*32+32).
    f32x4 acc[5][2];
    #pragma unroll
    for (int mi = 0; mi < 5; ++mi)
        #pragma unroll
        for (int ni = 0; ni < 2; ++ni)
            acc[mi][ni] = (f32x4){0.f, 0.f, 0.f, 0.f};

    #pragma unroll
    for (int kc = 0; kc < 8; ++kc) {
        short8 bfr[2];
        #pragma unroll
        for (int ni = 0; ni < 2; ++ni)
            bfr[ni] = *(const short8*)(wtb +
                ((kc * 256 + wv * 32 + ni * 16 + l15) << 5) + lq * 8);
        #pragma unroll
        for (int mi = 0; mi < 5; ++mi) {
            int row = mi * 16 + l15;
            short8 a = *(const short8*)(As + row * 256 +
                ((((kc << 2) | lq) ^ (row & 7)) << 3));
            acc[mi][0] = __builtin_amdgcn_mfma_f32_16x16x32_bf16(a, bfr[0], acc[mi][0], 0, 0, 0);
            acc[mi][1] = __builtin_amdgcn_mfma_f32_16x16x32_bf16(a, bfr[1], acc[mi][1], 0, 0, 0);
        }
    }
    __syncthreads();   // As dead; Ys live

    // ---- Phase 3: epilogue — per-wave LDS transpose, then coalesced
    //      float4 BN + residual + relu (68-float d-windows).
    float* yw = Ys + wv * 16 * YP;
    const int dbase0 = wv * 32;
    #pragma unroll
    for (int ni = 0; ni < 2; ++ni) {
        const int d_l = dbase0 + ni * 16 + l15;
        const int dm  = d_l % V;
        #pragma unroll
        for (int mi = 0; mi < 5; ++mi) {
            #pragma unroll
            for (int rg = 0; rg < 4; ++rg) {
                int row = mi * 16 + lq * 4 + rg;     // D frag: col=l15, row=lq*4+rg
                if (row < 68) {
                    int tl = row / V;
                    int u  = row - tl * V;
                    int v  = u + dm; if (v >= V) v -= V;
                    yw[l15 * YP + tl * V + v] = acc[mi][ni][rg];
                }
            }
        }
        __syncthreads();
        #pragma unroll
        for (int it = 0; it < 5; ++it) {
            int j = it * 64 + lane;                  // 272 float4 per wave-tile
            if (j < 272) {
                int dl  = j / 17;                    // 0..15
                int p4  = j - dl * 17;               // 0..16
                int d   = dbase0 + ni * 16 + dl;
                int pos = p4 * 4;
                int base = n * CTV + d * TV + tb * V + pos;
                float4 yv = *(const float4*)(yw + dl * YP + pos);
                float4 xv = *(const float4*)(x0 + base);
                float yy[4] = {yv.x, yv.y, yv.z, yv.w};
                float xx[4] = {xv.x, xv.y, xv.z, xv.w};
                int v = pos % V;
                float rr[4];
                #pragma unroll
                for (int e = 0; e < 4; ++e) {
                    float2 so = soff[v * C_DIM + d];
                    rr[e] = fmaxf(yy[e] * so.x + so.y + xx[e], 0.f);
                    if (++v == V) v = 0;
                }
                *(float4*)(out + base) = (float4){rr[0], rr[1], rr[2], rr[3]};
            }
        }
        __syncthreads();
    }
}

extern "C" void kernel_launch(void* const* d_in, const int* in_sizes, int n_in,
                              void* d_out, int out_size, void* d_ws, size_t ws_size,
                              hipStream_t stream)
{
    const float* x0    = (const float*)d_in[0];
    const float* fm    = (const float*)d_in[1];
    const float* W     = (const float*)d_in[2];
    const float* lb    = (const float*)d_in[3];
    const float* gamma = (const float*)d_in[4];
    const float* beta  = (const float*)d_in[5];
    const float* mean  = (const float*)d_in[6];
    const float* var   = (const float*)d_in[7];
    float* out = (float*)d_out;

    char* ws = (char*)d_ws;
    __hip_bfloat16* wtb = (__hip_bfloat16*)ws;
    float* g      = (float*)(ws + 131072);
    float2* soff  = (float2*)(ws + 148480);

    prep_kernel<<<256, 256, 0, stream>>>(fm, W, lb, gamma, beta, mean, var,
                                         wtb, g, soff);
    shiftgcn_kernel<<<1024, 512, 0, stream>>>(x0, wtb, g, soff, out);
}

// Round 7
// 74.414 us; speedup vs baseline: 1.0575x; 1.0575x over previous
//
#include <hip/hip_runtime.h>
#include <hip/hip_bf16.h>

#define V 17
#define C_DIM 256
#define TV 1088        // T*V
#define CTV 278528     // C*T*V
#define YP 76          // y LDS pitch in floats

typedef __attribute__((ext_vector_type(8))) short short8;
typedef __attribute__((ext_vector_type(4))) float f32x4;

static __device__ inline short f2bfs(float f) {
    union { __hip_bfloat16 b; short s; } u;
    u.b = __float2bfloat16(f);
    return u.s;
}

// ws layout (bytes):
//   0      : wtb   (65536 bf16)   blocked B^T: wtb[(kc*256+d)*32+kk] = W[kc*32+kk][d]
//   131072 : g     (4352 f32)     tanh(fm)+1
//   148480 : soff  (4352 float2)  {scale, off}
__global__ __launch_bounds__(256) void prep_kernel(
    const float* __restrict__ fm, const float* __restrict__ W,
    const float* __restrict__ lb, const float* __restrict__ gamma,
    const float* __restrict__ beta, const float* __restrict__ mean,
    const float* __restrict__ var,
    __hip_bfloat16* __restrict__ wtb, float* __restrict__ g,
    float2* __restrict__ soff)
{
    int i = blockIdx.x * 256 + threadIdx.x;   // 65536 threads
    int c = i >> 8, d = i & 255;
    float w = W[i];
    wtb[((c >> 5) * 256 + d) * 32 + (c & 31)] = __float2bfloat16(w);
    if (i < V * C_DIM) {
        g[i] = tanhf(fm[i]) + 1.0f;
        float sc = gamma[i] * rsqrtf(var[i] + 1e-5f);
        soff[i] = make_float2(sc, (lb[d] - mean[i]) * sc + beta[i]);
    }
}

// ---- staging task, monolithic (load+gate+cast+LDS write) ----
static __device__ __forceinline__ void stage_task(
    int t, short* As, const float* __restrict__ xplane, const float* __restrict__ g)
{
    int kkc = t / 68;                  // 16B slot index
    int r   = t - kkc * 68;            // 0..67
    int tl  = r / 17;
    int u   = r - tl * 17;
    int c0  = kkc * 8;
    const float* gp = g + u * C_DIM + c0;
    float4 g0 = *(const float4*)gp;
    float4 g1 = *(const float4*)(gp + 4);
    float gg[8] = {g0.x, g0.y, g0.z, g0.w, g1.x, g1.y, g1.z, g1.w};
    const float* xb = xplane + tl * V;
    int mm = (u + c0) % V;
    float xv[8];
    #pragma unroll
    for (int i = 0; i < 8; ++i) {
        xv[i] = xb[(c0 + i) * TV + mm];
        mm = (mm == V - 1) ? 0 : mm + 1;
    }
    short av[8];
    #pragma unroll
    for (int i = 0; i < 8; ++i) av[i] = f2bfs(xv[i] * gg[i]);
    *(short8*)(As + r * 256 + ((kkc ^ (r & 7)) << 3)) =
        (short8){av[0], av[1], av[2], av[3], av[4], av[5], av[6], av[7]};
}

// ---- split staging: issue loads now, write LDS later (T14) ----
static __device__ __forceinline__ void stage_load(
    int t, const float* __restrict__ xplane, const float* __restrict__ g,
    float xv[8], float gg[8], int* waddr)
{
    int kkc = t / 68;
    int r   = t - kkc * 68;
    int tl  = r / 17;
    int u   = r - tl * 17;
    int c0  = kkc * 8;
    const float* gp = g + u * C_DIM + c0;
    float4 g0 = *(const float4*)gp;
    float4 g1 = *(const float4*)(gp + 4);
    gg[0]=g0.x; gg[1]=g0.y; gg[2]=g0.z; gg[3]=g0.w;
    gg[4]=g1.x; gg[5]=g1.y; gg[6]=g1.z; gg[7]=g1.w;
    const float* xb = xplane + tl * V;
    int mm = (u + c0) % V;
    #pragma unroll
    for (int i = 0; i < 8; ++i) {
        xv[i] = xb[(c0 + i) * TV + mm];
        mm = (mm == V - 1) ? 0 : mm + 1;
    }
    *waddr = r * 256 + ((kkc ^ (r & 7)) << 3);
}

static __device__ __forceinline__ void stage_write(
    short* As, const float xv[8], const float gg[8], int waddr)
{
    short av[8];
    #pragma unroll
    for (int i = 0; i < 8; ++i) av[i] = f2bfs(xv[i] * gg[i]);
    *(short8*)(As + waddr) =
        (short8){av[0], av[1], av[2], av[3], av[4], av[5], av[6], av[7]};
}

// Block: 4 whole t-groups (68 rows, padded to 80), all 256 d. 512 thr / 8 waves.
// A-tile LDS: [80 rows][256 halves], 16B-slot XOR swizzle (slot ^= row&7).
// Schedule: stage K-half0 | barrier | issue half1 loads -> MFMA half0 ->
// write half1 | barrier | MFMA half1 | epilogue w/ issue-early residual loads.
__global__ __launch_bounds__(512, 4) void shiftgcn_kernel(
    const float* __restrict__ x0, const __hip_bfloat16* __restrict__ wtb,
    const float* __restrict__ g, const float2* __restrict__ soff,
    float* __restrict__ out)
{
    __shared__ __align__(16) char smem[80 * 256 * 2];   // 40960 B
    short* As = (short*)smem;                 // [80 rows][256 halves], swizzled
    float* Ys = (float*)smem;                 // epilogue union: [8 waves][16 d][YP]

    const int tid  = threadIdx.x;
    const int lane = tid & 63;
    const int wv   = tid >> 6;                // 0..7
    const int l15  = lane & 15;
    const int lq   = lane >> 4;

    // T1: 1024 wg = 8 XCD x 128 contiguous tiles (bijective)
    const int wg  = (blockIdx.x & 7) * 128 + (blockIdx.x >> 3);
    const int nt0 = wg * 4;
    const int n   = nt0 >> 6;
    const int tb  = nt0 & 63;                 // multiple of 4
    const float* xplane = x0 + n * CTV + tb * V;   // + c*TV + tl*V + joint

    // zero pad rows 68..79 (12 rows * 256 halves = 384 short8)
    if (tid < 384) ((short8*)(As + 68 * 256))[tid] = (short8)0;

    // ---- Phase 1a: stage K-half0 (kkc 0..15, tasks 0..1087) + half1's tail
    stage_task(tid, As, xplane, g);
    stage_task(512 + tid, As, xplane, g);
    if (tid < 64) {
        stage_task(1024 + tid, As, xplane, g);   // half0 tail
        stage_task(2112 + tid, As, xplane, g);   // half1 tail (early, harmless)
    }
    __syncthreads();

    // ---- Phase 1b loads: issue half1 gathers (kkc 16..31) into registers
    float xa[8], ga[8], xb2[8], gb[8];
    int wa, wb;
    stage_load(1088 + tid, xplane, g, xa, ga, &wa);
    stage_load(1600 + tid, xplane, g, xb2, gb, &wb);

    // ---- Phase 2 half0: MFMA kc 0..3 (loads above drain underneath)
    f32x4 acc[5][2];
    #pragma unroll
    for (int mi = 0; mi < 5; ++mi)
        #pragma unroll
        for (int ni = 0; ni < 2; ++ni)
            acc[mi][ni] = (f32x4){0.f, 0.f, 0.f, 0.f};

    #pragma unroll
    for (int kc = 0; kc < 4; ++kc) {
        short8 bfr[2];
        #pragma unroll
        for (int ni = 0; ni < 2; ++ni)
            bfr[ni] = *(const short8*)(wtb +
                ((kc * 256 + wv * 32 + ni * 16 + l15) << 5) + lq * 8);
        #pragma unroll
        for (int mi = 0; mi < 5; ++mi) {
            int row = mi * 16 + l15;
            short8 a = *(const short8*)(As + row * 256 +
                ((((kc << 2) | lq) ^ (row & 7)) << 3));
            acc[mi][0] = __builtin_amdgcn_mfma_f32_16x16x32_bf16(a, bfr[0], acc[mi][0], 0, 0, 0);
            acc[mi][1] = __builtin_amdgcn_mfma_f32_16x16x32_bf16(a, bfr[1], acc[mi][1], 0, 0, 0);
        }
    }

    // ---- Phase 1b writes: half1 into LDS
    stage_write(As, xa, ga, wa);
    stage_write(As, xb2, gb, wb);
    __syncthreads();

    // ---- Phase 2 half1: MFMA kc 4..7
    #pragma unroll
    for (int kc = 4; kc < 8; ++kc) {
        short8 bfr[2];
        #pragma unroll
        for (int ni = 0; ni < 2; ++ni)
            bfr[ni] = *(const short8*)(wtb +
                ((kc * 256 + wv * 32 + ni * 16 + l15) << 5) + lq * 8);
        #pragma unroll
        for (int mi = 0; mi < 5; ++mi) {
            int row = mi * 16 + l15;
            short8 a = *(const short8*)(As + row * 256 +
                ((((kc << 2) | lq) ^ (row & 7)) << 3));
            acc[mi][0] = __builtin_amdgcn_mfma_f32_16x16x32_bf16(a, bfr[0], acc[mi][0], 0, 0, 0);
            acc[mi][1] = __builtin_amdgcn_mfma_f32_16x16x32_bf16(a, bfr[1], acc[mi][1], 0, 0, 0);
        }
    }
    __syncthreads();   // As dead; Ys live

    // ---- Phase 3: epilogue. Residual loads issued BEFORE the transpose
    //      barrier (independent of LDS), consumed after.
    float* yw = Ys + wv * 16 * YP;
    const int dbase0 = wv * 32;
    #pragma unroll
    for (int ni = 0; ni < 2; ++ni) {
        // issue-early residual reads
        float4 xr[5];
        #pragma unroll
        for (int it = 0; it < 5; ++it) {
            int j = it * 64 + lane;
            if (j < 272) {
                int dl  = j / 17;
                int p4  = j - dl * 17;
                int d   = dbase0 + ni * 16 + dl;
                int pos = p4 * 4;
                xr[it] = *(const float4*)(x0 + n * CTV + d * TV + tb * V + pos);
            }
        }
        // transpose acc -> yw
        const int d_l = dbase0 + ni * 16 + l15;
        const int dm  = d_l % V;
        #pragma unroll
        for (int mi = 0; mi < 5; ++mi) {
            #pragma unroll
            for (int rg = 0; rg < 4; ++rg) {
                int row = mi * 16 + lq * 4 + rg;     // D frag: col=l15, row=lq*4+rg
                if (row < 68) {
                    int tl = row / V;
                    int u  = row - tl * V;
                    int v  = u + dm; if (v >= V) v -= V;
                    yw[l15 * YP + tl * V + v] = acc[mi][ni][rg];
                }
            }
        }
        __syncthreads();
        // BN + residual + relu, coalesced float4
        #pragma unroll
        for (int it = 0; it < 5; ++it) {
            int j = it * 64 + lane;
            if (j < 272) {
                int dl  = j / 17;
                int p4  = j - dl * 17;
                int d   = dbase0 + ni * 16 + dl;
                int pos = p4 * 4;
                int base = n * CTV + d * TV + tb * V + pos;
                float4 yv = *(const float4*)(yw + dl * YP + pos);
                float yy[4] = {yv.x, yv.y, yv.z, yv.w};
                float xx[4] = {xr[it].x, xr[it].y, xr[it].z, xr[it].w};
                int v = pos % V;
                float rr[4];
                #pragma unroll
                for (int e = 0; e < 4; ++e) {
                    float2 so = soff[v * C_DIM + d];
                    rr[e] = fmaxf(yy[e] * so.x + so.y + xx[e], 0.f);
                    if (++v == V) v = 0;
                }
                *(float4*)(out + base) = (float4){rr[0], rr[1], rr[2], rr[3]};
            }
        }
        __syncthreads();
    }
}

extern "C" void kernel_launch(void* const* d_in, const int* in_sizes, int n_in,
                              void* d_out, int out_size, void* d_ws, size_t ws_size,
                              hipStream_t stream)
{
    const float* x0    = (const float*)d_in[0];
    const float* fm    = (const float*)d_in[1];
    const float* W     = (const float*)d_in[2];
    const float* lb    = (const float*)d_in[3];
    const float* gamma = (const float*)d_in[4];
    const float* beta  = (const float*)d_in[5];
    const float* mean  = (const float*)d_in[6];
    const float* var   = (const float*)d_in[7];
    float* out = (float*)d_out;

    char* ws = (char*)d_ws;
    __hip_bfloat16* wtb = (__hip_bfloat16*)ws;
    float* g      = (float*)(ws + 131072);
    float2* soff  = (float2*)(ws + 148480);

    prep_kernel<<<256, 256, 0, stream>>>(fm, W, lb, gamma, beta, mean, var,
                                         wtb, g, soff);
    shiftgcn_kernel<<<1024, 512, 0, stream>>>(x0, wtb, g, soff, out);
}

// Round 8
// 70.099 us; speedup vs baseline: 1.1226x; 1.0616x over previous
//
#include <hip/hip_runtime.h>
#include <hip/hip_bf16.h>

#define V 17
#define C_DIM 256
#define TV 1088        // T*V
#define CTV 278528     // C*T*V
#define YP 76          // y LDS pitch in floats

typedef __attribute__((ext_vector_type(8))) short short8;
typedef __attribute__((ext_vector_type(4))) float f32x4;

static __device__ inline short f2bfs(float f) {
    union { __hip_bfloat16 b; short s; } u;
    u.b = __float2bfloat16(f);
    return u.s;
}
static __device__ inline float bfs2f(short s) {
    union { float f; unsigned u; } q;
    q.u = ((unsigned)(unsigned short)s) << 16;
    return q.f;
}

// ws layout (bytes):
//   0      : wtb  (65536 bf16)   blocked B^T: wtb[(kc*256+d)*32+kk] = W[kc*32+kk][d]
//   131072 : g    (4352 f32)     tanh(fm)+1
//   148480 : sox  (4352 float4)  [v][d] = {scale, off, 1/g[(v-d)%17][d], 0}
__global__ __launch_bounds__(256) void prep_kernel(
    const float* __restrict__ fm, const float* __restrict__ W,
    const float* __restrict__ lb, const float* __restrict__ gamma,
    const float* __restrict__ beta, const float* __restrict__ mean,
    const float* __restrict__ var,
    __hip_bfloat16* __restrict__ wtb, float* __restrict__ g,
    float4* __restrict__ sox)
{
    int i = blockIdx.x * 256 + threadIdx.x;   // 65536 threads
    int c = i >> 8, d = i & 255;
    float w = W[i];
    wtb[((c >> 5) * 256 + d) * 32 + (c & 31)] = __float2bfloat16(w);
    if (i < V * C_DIM) {
        g[i] = tanhf(fm[i]) + 1.0f;
        int v = i >> 8;                        // joint index for this row
        float sc = gamma[i] * rsqrtf(var[i] + 1e-5f);
        float of = (lb[d] - mean[i]) * sc + beta[i];
        int u = v - d % V; if (u < 0) u += V;  // (v - d) mod 17
        float gu = tanhf(fm[u * C_DIM + d]) + 1.0f;
        sox[i] = make_float4(sc, of, 1.0f / gu, 0.0f);
    }
}

// ---- staging task: gather 8 channels for row r, gate, cast, one short8 write
static __device__ __forceinline__ void stage_task(
    int t, short* As, const float* __restrict__ xplane, const float* __restrict__ g)
{
    int kkc = t / 68;                  // 16B slot index
    int r   = t - kkc * 68;            // 0..67
    int tl  = r / 17;
    int u   = r - tl * 17;
    int c0  = kkc * 8;
    const float* gp = g + u * C_DIM + c0;
    float4 g0 = *(const float4*)gp;
    float4 g1 = *(const float4*)(gp + 4);
    float gg[8] = {g0.x, g0.y, g0.z, g0.w, g1.x, g1.y, g1.z, g1.w};
    const float* xb = xplane + tl * V;
    int mm = (u + c0) % V;
    float xv[8];
    #pragma unroll
    for (int i = 0; i < 8; ++i) {
        xv[i] = xb[(c0 + i) * TV + mm];
        mm = (mm == V - 1) ? 0 : mm + 1;
    }
    short av[8];
    #pragma unroll
    for (int i = 0; i < 8; ++i) av[i] = f2bfs(xv[i] * gg[i]);
    *(short8*)(As + r * 256 + ((kkc ^ (r & 7)) << 3)) =
        (short8){av[0], av[1], av[2], av[3], av[4], av[5], av[6], av[7]};
}

// Block: 4 whole t-groups (68 rows, padded to 80), all 256 d. 512 thr / 8 waves.
// A-tile LDS: [80 rows][256 halves], 16B-slot XOR swizzle (slot ^= row&7).
// As stays LIVE through the epilogue: the residual x0[n,d,t,v] is recovered
// from As[r,d]*ginv (shift_in/out are inverse rotations -> at c==d the input
// joint equals the output joint). No second global pass over x0.
__global__ __launch_bounds__(512, 4) void shiftgcn_kernel(
    const float* __restrict__ x0, const __hip_bfloat16* __restrict__ wtb,
    const float* __restrict__ g, const float4* __restrict__ sox,
    float* __restrict__ out)
{
    __shared__ __align__(16) char smem[80 * 256 * 2 + 8 * 16 * YP * 4]; // 79872 B
    short* As = (short*)smem;                 // [80 rows][256 halves], swizzled
    float* Ys = (float*)(smem + 80 * 256 * 2);// [8 waves][16 d][YP]

    const int tid  = threadIdx.x;
    const int lane = tid & 63;
    const int wv   = tid >> 6;                // 0..7
    const int l15  = lane & 15;
    const int lq   = lane >> 4;

    // T1: 1024 wg = 8 XCD x 128 contiguous tiles (bijective)
    const int wg  = (blockIdx.x & 7) * 128 + (blockIdx.x >> 3);
    const int nt0 = wg * 4;
    const int n   = nt0 >> 6;
    const int tb  = nt0 & 63;                 // multiple of 4
    const float* xplane = x0 + n * CTV + tb * V;   // + c*TV + tl*V + joint

    // zero pad rows 68..79 (12 rows * 256 halves = 384 short8)
    if (tid < 384) ((short8*)(As + 68 * 256))[tid] = (short8)0;

    // ---- Phase 1: stage all K. 2176 tasks = 4 full rounds + 128-thread tail.
    #pragma unroll 1
    for (int it = 0; it < 4; ++it)
        stage_task(it * 512 + tid, As, xplane, g);
    if (tid < 128)
        stage_task(2048 + tid, As, xplane, g);
    __syncthreads();

    // ---- Phase 2: MFMA, no barriers. Wave wv owns cols [wv*32, wv*32+32).
    f32x4 acc[5][2];
    #pragma unroll
    for (int mi = 0; mi < 5; ++mi)
        #pragma unroll
        for (int ni = 0; ni < 2; ++ni)
            acc[mi][ni] = (f32x4){0.f, 0.f, 0.f, 0.f};

    #pragma unroll
    for (int kc = 0; kc < 8; ++kc) {
        short8 bfr[2];
        #pragma unroll
        for (int ni = 0; ni < 2; ++ni)
            bfr[ni] = *(const short8*)(wtb +
                ((kc * 256 + wv * 32 + ni * 16 + l15) << 5) + lq * 8);
        #pragma unroll
        for (int mi = 0; mi < 5; ++mi) {
            int row = mi * 16 + l15;
            short8 a = *(const short8*)(As + row * 256 +
                ((((kc << 2) | lq) ^ (row & 7)) << 3));
            acc[mi][0] = __builtin_amdgcn_mfma_f32_16x16x32_bf16(a, bfr[0], acc[mi][0], 0, 0, 0);
            acc[mi][1] = __builtin_amdgcn_mfma_f32_16x16x32_bf16(a, bfr[1], acc[mi][1], 0, 0, 0);
        }
    }
    __syncthreads();

    // ---- Phase 3: epilogue — per-wave LDS transpose, then coalesced float4
    //      BN + residual(from As) + relu writes (68-float d-windows).
    float* yw = Ys + wv * 16 * YP;
    const int dbase0 = wv * 32;
    #pragma unroll
    for (int ni = 0; ni < 2; ++ni) {
        const int d_l = dbase0 + ni * 16 + l15;
        const int dm  = d_l % V;
        #pragma unroll
        for (int mi = 0; mi < 5; ++mi) {
            #pragma unroll
            for (int rg = 0; rg < 4; ++rg) {
                int row = mi * 16 + lq * 4 + rg;     // D frag: col=l15, row=lq*4+rg
                if (row < 68) {
                    int tl = row / V;
                    int u  = row - tl * V;
                    int v  = u + dm; if (v >= V) v -= V;
                    yw[l15 * YP + tl * V + v] = acc[mi][ni][rg];
                }
            }
        }
        __syncthreads();
        #pragma unroll
        for (int it = 0; it < 5; ++it) {
            int j = it * 64 + lane;                  // 272 float4 per wave-tile
            if (j < 272) {
                int dl   = j / 17;                   // 0..15
                int p4   = j - dl * 17;              // 0..16
                int d    = dbase0 + ni * 16 + dl;
                int dm17 = d % V;
                int pos  = p4 * 4;                   // 0..64
                int base = n * CTV + d * TV + tb * V + pos;
                float4 yv = *(const float4*)(yw + dl * YP + pos);
                float yy[4] = {yv.x, yv.y, yv.z, yv.w};
                int v  = pos % V;
                int tl = pos / V;
                int u  = v - dm17; if (u < 0) u += V;
                float rr[4];
                #pragma unroll
                for (int e = 0; e < 4; ++e) {
                    float4 so = sox[v * C_DIM + d];
                    // residual: x0[n,d,t,v] = bf16(x*g)[row=tl*17+u, col=d] / g
                    int r  = tl * V + u;
                    int ha = r * 256 + ((((d >> 3) ^ (r & 7)) << 3) | (d & 7));
                    float x = bfs2f(As[ha]) * so.z;
                    rr[e] = fmaxf(yy[e] * so.x + so.y + x, 0.f);
                    ++v; ++u;
                    if (v == V) { v = 0; ++tl; }
                    if (u == V) u = 0;
                }
                *(float4*)(out + base) = (float4){rr[0], rr[1], rr[2], rr[3]};
            }
        }
        __syncthreads();
    }
}

extern "C" void kernel_launch(void* const* d_in, const int* in_sizes, int n_in,
                              void* d_out, int out_size, void* d_ws, size_t ws_size,
                              hipStream_t stream)
{
    const float* x0    = (const float*)d_in[0];
    const float* fm    = (const float*)d_in[1];
    const float* W     = (const float*)d_in[2];
    const float* lb    = (const float*)d_in[3];
    const float* gamma = (const float*)d_in[4];
    const float* beta  = (const float*)d_in[5];
    const float* mean  = (const float*)d_in[6];
    const float* var   = (const float*)d_in[7];
    float* out = (float*)d_out;

    char* ws = (char*)d_ws;
    __hip_bfloat16* wtb = (__hip_bfloat16*)ws;
    float*  g   = (float*)(ws + 131072);
    float4* sox = (float4*)(ws + 148480);

    prep_kernel<<<256, 256, 0, stream>>>(fm, W, lb, gamma, beta, mean, var,
                                         wtb, g, sox);
    shiftgcn_kernel<<<1024, 512, 0, stream>>>(x0, wtb, g, sox, out);
}

// Round 10
// 66.882 us; speedup vs baseline: 1.1766x; 1.0481x over previous
//
#include <hip/hip_runtime.h>
#include <hip/hip_bf16.h>

#define V 17
#define C_DIM 256
#define TV 1088        // T*V
#define CTV 278528     // C*T*V

typedef __attribute__((ext_vector_type(8))) short short8;
typedef __attribute__((ext_vector_type(4))) short svec4;
typedef __attribute__((ext_vector_type(4))) float f32x4;

static __device__ inline short f2bfs(float f) {
    union { __hip_bfloat16 b; short s; } u;
    u.b = __float2bfloat16(f);
    return u.s;
}
static __device__ inline float bfs2f(short s) {
    union { float f; unsigned u; } q;
    q.u = ((unsigned)(unsigned short)s) << 16;
    return q.f;
}

// ws layout (bytes):
//   0      : wtb (65536 bf16)  blocked W^T: wtb[(kc*256+d)*32+kk] = W[kc*32+kk][d]
//   131072 : g   (4352 f32)    tanh(fm)+1
//   148480 : scl (4352 f32)    [u][d] = gamma[v,d]/sqrt(var[v,d]+eps),  v=(u+d)%17
//   165888 : ofs (4352 f32)    [u][d] = (lin_b[d]-mean[v,d])*scl+beta[v,d]
//   183296 : gnv (4352 f32)    [u][d] = 1/g[u][d]
__global__ __launch_bounds__(256) void prep_kernel(
    const float* __restrict__ fm, const float* __restrict__ W,
    const float* __restrict__ lb, const float* __restrict__ gamma,
    const float* __restrict__ beta, const float* __restrict__ mean,
    const float* __restrict__ var,
    __hip_bfloat16* __restrict__ wtb, float* __restrict__ g,
    float* __restrict__ scl, float* __restrict__ ofs, float* __restrict__ gnv)
{
    int i = blockIdx.x * 256 + threadIdx.x;   // 65536 threads
    int c = i >> 8, d = i & 255;
    float w = W[i];
    wtb[((c >> 5) * 256 + d) * 32 + (c & 31)] = __float2bfloat16(w);
    if (i < V * C_DIM) {
        float gv = tanhf(fm[i]) + 1.0f;
        g[i]   = gv;
        gnv[i] = 1.0f / gv;
        int u = i >> 8;                        // GEMM-row joint
        int v = u + d; v %= V;                 // OUTPUT joint = (u+d) mod 17
        int k = v * C_DIM + d;                 // BN parameter index
        float sc = gamma[k] * rsqrtf(var[k] + 1e-5f);
        scl[i] = sc;
        ofs[i] = (lb[d] - mean[k]) * sc + beta[k];
    }
}

// ---- staging task: gather 8 channels for row r, gate, cast, one short8 write
static __device__ __forceinline__ void stage_task(
    int t, short* As, const float* __restrict__ xplane, const float* __restrict__ g)
{
    int kkc = t / 68;                  // 16B slot index
    int r   = t - kkc * 68;            // 0..67
    int tl  = r / 17;
    int u   = r - tl * 17;
    int c0  = kkc * 8;
    const float* gp = g + u * C_DIM + c0;
    float4 g0 = *(const float4*)gp;
    float4 g1 = *(const float4*)(gp + 4);
    float gg[8] = {g0.x, g0.y, g0.z, g0.w, g1.x, g1.y, g1.z, g1.w};
    const float* xb = xplane + tl * V;
    int mm = (u + c0) % V;
    float xv[8];
    #pragma unroll
    for (int i = 0; i < 8; ++i) {
        xv[i] = xb[(c0 + i) * TV + mm];
        mm = (mm == V - 1) ? 0 : mm + 1;
    }
    short av[8];
    #pragma unroll
    for (int i = 0; i < 8; ++i) av[i] = f2bfs(xv[i] * gg[i]);
    *(short8*)(As + r * 256 + ((kkc ^ (r & 7)) << 3)) =
        (short8){av[0], av[1], av[2], av[3], av[4], av[5], av[6], av[7]};
}

// Block: 4 whole t-groups (68 GEMM rows, padded to 80), all 256 d.
// 512 thr / 8 waves. A-tile LDS: [80 rows][256 halves], XOR swizzle.
// MFMA with SWAPPED operands: D = W^T x X^T -> lane col (l15) = GEMM row pos,
// output row (lq*4+rg) = d. Store applies the OUTPUT SHIFT: value (pos,d)
// goes to joint v = (pos%17 + d) % 17 in the same t-row (r9 bug: stored at
// joint pos%17). Residual x0[n,d,t,v] recovered from As[pos][d]*(1/g[u][d]).
__global__ __launch_bounds__(512, 4) void shiftgcn_kernel(
    const float* __restrict__ x0, const __hip_bfloat16* __restrict__ wtb,
    const float* __restrict__ g, const float* __restrict__ scl,
    const float* __restrict__ ofs, const float* __restrict__ gnv,
    float* __restrict__ out)
{
    __shared__ __align__(16) short As[80 * 256];   // 40960 B

    const int tid  = threadIdx.x;
    const int lane = tid & 63;
    const int wv   = tid >> 6;                // 0..7
    const int l15  = lane & 15;
    const int lq   = lane >> 4;

    // T1: 1024 wg = 8 XCD x 128 contiguous tiles (bijective)
    const int wg  = (blockIdx.x & 7) * 128 + (blockIdx.x >> 3);
    const int nt0 = wg * 4;
    const int n   = nt0 >> 6;
    const int tb  = nt0 & 63;                 // multiple of 4
    const float* xplane = x0 + n * CTV + tb * V;   // + c*TV + tl*V + joint

    // zero pad rows 68..79 (12 rows * 256 halves = 384 short8)
    if (tid < 384) ((short8*)(As + 68 * 256))[tid] = (short8)0;

    // ---- Phase 1: stage all K. 2176 tasks = 4 full rounds + 128-thread tail.
    #pragma unroll 1
    for (int it = 0; it < 4; ++it)
        stage_task(it * 512 + tid, As, xplane, g);
    if (tid < 128)
        stage_task(2048 + tid, As, xplane, g);
    __syncthreads();   // the ONLY barrier

    // ---- Phase 2: MFMA, swapped operands. Wave wv owns d in [wv*32,wv*32+32).
    f32x4 acc[2][5];   // [dTile][posTile]
    #pragma unroll
    for (int ni = 0; ni < 2; ++ni)
        #pragma unroll
        for (int mi = 0; mi < 5; ++mi)
            acc[ni][mi] = (f32x4){0.f, 0.f, 0.f, 0.f};

    #pragma unroll
    for (int kc = 0; kc < 8; ++kc) {
        short8 wfr[2];
        #pragma unroll
        for (int ni = 0; ni < 2; ++ni)
            wfr[ni] = *(const short8*)(wtb +
                ((kc * 256 + wv * 32 + ni * 16 + l15) << 5) + lq * 8);
        #pragma unroll
        for (int mi = 0; mi < 5; ++mi) {
            int row = mi * 16 + l15;
            short8 a = *(const short8*)(As + row * 256 +
                ((((kc << 2) | lq) ^ (row & 7)) << 3));
            acc[0][mi] = __builtin_amdgcn_mfma_f32_16x16x32_bf16(wfr[0], a, acc[0][mi], 0, 0, 0);
            acc[1][mi] = __builtin_amdgcn_mfma_f32_16x16x32_bf16(wfr[1], a, acc[1][mi], 0, 0, 0);
        }
    }

    // ---- Phase 3: direct epilogue. Lane holds GEMM row pos = mi*16+l15
    //      (joint ur = pos%17), d = wv*32 + ni*16 + lq*4 + rg. Output joint
    //      vv = (ur + d) % 17. Tables indexed [ur][d] -> float4 loads.
    #pragma unroll
    for (int ni = 0; ni < 2; ++ni) {
        const int D0 = wv * 32 + ni * 16 + lq * 4;
        const int dm = D0 % V;
        int tl = 0, ur = l15;                 // pos = tl*17 + ur
        #pragma unroll
        for (int mi = 0; mi < 5; ++mi) {
            int pos = mi * 16 + l15;
            if (pos < 68) {
                float4 s4 = *(const float4*)(scl + ur * C_DIM + D0);
                float4 o4 = *(const float4*)(ofs + ur * C_DIM + D0);
                float4 g4 = *(const float4*)(gnv + ur * C_DIM + D0);
                float ss[4] = {s4.x, s4.y, s4.z, s4.w};
                float oo[4] = {o4.x, o4.y, o4.z, o4.w};
                float gi[4] = {g4.x, g4.y, g4.z, g4.w};
                // residual: 4 consecutive bf16 at As[pos][D0..D0+3]
                int hb = pos * 256 + ((((D0 >> 3) ^ (pos & 7)) << 3) | (D0 & 7));
                svec4 a4 = *(const svec4*)(As + hb);
                int vv = ur + dm; if (vv >= V) vv -= V;   // output joint, rg=0
                int base2 = n * CTV + D0 * TV + (tb + tl) * V;
                #pragma unroll
                for (int rg = 0; rg < 4; ++rg) {
                    float x = bfs2f(a4[rg]) * gi[rg];
                    float val = acc[ni][mi][rg] * ss[rg] + oo[rg] + x;
                    out[base2 + rg * TV + vv] = fmaxf(val, 0.f);
                    if (++vv == V) vv = 0;
                }
            }
            // pos += 16  =>  (ur==0) ? ur=16 : (ur-=1, tl+=1)
            if (ur == 0) ur = 16; else { ur -= 1; tl += 1; }
        }
    }
}

extern "C" void kernel_launch(void* const* d_in, const int* in_sizes, int n_in,
                              void* d_out, int out_size, void* d_ws, size_t ws_size,
                              hipStream_t stream)
{
    const float* x0    = (const float*)d_in[0];
    const float* fm    = (const float*)d_in[1];
    const float* W     = (const float*)d_in[2];
    const float* lb    = (const float*)d_in[3];
    const float* gamma = (const float*)d_in[4];
    const float* beta  = (const float*)d_in[5];
    const float* mean  = (const float*)d_in[6];
    const float* var   = (const float*)d_in[7];
    float* out = (float*)d_out;

    char* ws = (char*)d_ws;
    __hip_bfloat16* wtb = (__hip_bfloat16*)ws;
    float* g   = (float*)(ws + 131072);
    float* scl = (float*)(ws + 148480);
    float* ofs = (float*)(ws + 165888);
    float* gnv = (float*)(ws + 183296);

    prep_kernel<<<256, 256, 0, stream>>>(fm, W, lb, gamma, beta, mean, var,
                                         wtb, g, scl, ofs, gnv);
    shiftgcn_kernel<<<1024, 512, 0, stream>>>(x0, wtb, g, scl, ofs, gnv, out);
}